// Round 10
// baseline (276.387 us; speedup 1.0000x reference)
//
#include <hip/hip_runtime.h>
#include <stdint.h>

// ---------------------------------------------------------------------------
// TokenAlignerOT: A = cos(X,Y); K = exp(10A); ONE unbalanced-Sinkhorn
// iteration; T = (log K)/10 * (u K v^T) + delta; out = T @ X.
// Round 10 GEMM: 128x128 tile, BK=32, 4 waves, 32 KiB LDS, 4 blocks/CU
// (m97's verified cross-block-TLP operating point) + T2 both-sides swizzle
// (2-way alias only) + gload16 staging + asm ds_read + raw barriers +
// counted vmcnt drain at tile end (stall hidden by 3 other resident blocks).
// GEMM1 grid 1024 (4/CU); GEMM2 split-K=2 grid 1024, f32 atomicAdd.
// Workspace: 80 MiB + 64 KiB of d_ws.
// ---------------------------------------------------------------------------

typedef __attribute__((ext_vector_type(8))) __bf16 bf16x8;
typedef __attribute__((ext_vector_type(4))) float f32x4;
typedef __attribute__((ext_vector_type(8))) unsigned short ushort8;

#define N_TOK 4096
#define D_EMB 2048
#define FI 0.009900990099009901f   /* reg_m/(reg_m+reg) = 0.001/0.101 */
#define LOG2A (-12.0f)             /* log2(1/4096) */

__device__ __forceinline__ unsigned short f2bf(float f) {
  union { float f; uint32_t u; } c; c.f = f;
  uint32_t r = (c.u + 0x7FFFu + ((c.u >> 16) & 1u)) >> 16;
  return (unsigned short)r;
}
__device__ __forceinline__ float bf2f(unsigned short h) {
  union { uint32_t u; float f; } c; c.u = ((uint32_t)h) << 16;
  return c.f;
}
__device__ __forceinline__ float pow_fi_of(float s) {
  return exp2f(FI * (LOG2A - log2f(s)));
}

// async global->LDS, 16 B per lane; LDS dest is wave-uniform base (+lane*16 HW)
typedef const __attribute__((address_space(1))) unsigned int* as1_u32p;
typedef __attribute__((address_space(3))) unsigned int* as3_u32p;
__device__ __forceinline__ void gload16(const void* g, void* l) {
  __builtin_amdgcn_global_load_lds((as1_u32p)g, (as3_u32p)l, 16, 0, 0);
}

// inline-asm LDS read: invisible to SIInsertWaitcnts' LDS-DMA aliasing.
typedef __attribute__((address_space(3))) const char* lds_cp;
__device__ __forceinline__ bf16x8 ds_read16(lds_cp p) {
  bf16x8 r;
  asm volatile("ds_read_b128 %0, %1" : "=v"(r) : "v"(p));
  return r;
}

__device__ __forceinline__ void bar_raw() {
  asm volatile("s_barrier" ::: "memory");
}
__device__ __forceinline__ void sb0() { __builtin_amdgcn_sched_barrier(0); }
__device__ __forceinline__ void lgkm_wait0() {
  asm volatile("s_waitcnt lgkmcnt(0)" ::: "memory");
}

// --------------------------- row L2-normalize -> bf16 ----------------------
__global__ __launch_bounds__(256) void rownorm_bf16(const float* __restrict__ in,
                                                    unsigned short* __restrict__ out) {
  const int row = blockIdx.x;
  const int t = threadIdx.x;
  const float* r = in + (size_t)row * D_EMB;
  float4 a = *(const float4*)(r + t * 8);
  float4 b = *(const float4*)(r + t * 8 + 4);
  float s = a.x * a.x + a.y * a.y + a.z * a.z + a.w * a.w
          + b.x * b.x + b.y * b.y + b.z * b.z + b.w * b.w;
#pragma unroll
  for (int off = 32; off; off >>= 1) s += __shfl_xor(s, off);
  __shared__ float wsum[4];
  if ((t & 63) == 0) wsum[t >> 6] = s;
  __syncthreads();
  float tot = wsum[0] + wsum[1] + wsum[2] + wsum[3];
  float scale = 1.0f / fmaxf(sqrtf(tot), 1e-8f);
  ushort8 o;
  o[0] = f2bf(a.x * scale); o[1] = f2bf(a.y * scale);
  o[2] = f2bf(a.z * scale); o[3] = f2bf(a.w * scale);
  o[4] = f2bf(b.x * scale); o[5] = f2bf(b.y * scale);
  o[6] = f2bf(b.z * scale); o[7] = f2bf(b.w * scale);
  *(ushort8*)(out + (size_t)row * D_EMB + t * 8) = o;
}

// --------------------------- transpose X -> bf16 X^T ------------------------
__global__ __launch_bounds__(256) void transpose_f32_to_bf16(
    const float* __restrict__ in, unsigned short* __restrict__ out, int R, int C) {
  __shared__ float tile[32][33];
  const int bi = blockIdx.y * 32, bj = blockIdx.x * 32;
  const int tx = threadIdx.x, ty = threadIdx.y;
#pragma unroll
  for (int dy = 0; dy < 32; dy += 8)
    tile[ty + dy][tx] = in[(size_t)(bi + ty + dy) * C + bj + tx];
  __syncthreads();
#pragma unroll
  for (int dy = 0; dy < 32; dy += 8)
    out[(size_t)(bj + ty + dy) * R + bi + tx] = f2bf(tile[tx][ty + dy]);
}

// ----------------- 128x128 NT GEMM, BK=32, 4 waves, 4 blocks/CU ------------
// C[i][j] = sum_k A[i][k]*B[j][k]; A:[M][ldA], B:[N][ldB] row-major bf16.
// 256 thr = 4 waves (2Mx2N), per-wave 64x64. LDS 32 KiB = 2buf x (A 8K + B 8K).
// Rows are 64B (32 bf16) = 4 chunks of 16B; physical chunk c holds logical
// chunk c ^ ((row>>1)&3): staging pre-swizzles the GLOBAL column, gload16
// dest stays linear, asm ds_read applies the same involution -> 2-way bank
// alias only (free). One barrier + vmcnt(0) per tile; the drain stall hides
// under the 3 other co-resident blocks (m97/m114 cross-block TLP).
// EPI==0: outK = bf16(exp(10*C)) + fused rowsum atomics. EPI==1: atomicAdd.
template <int EPI>
__global__ __launch_bounds__(256, 4) void gemm128(
    const unsigned short* __restrict__ Amat, const unsigned short* __restrict__ Bmat,
    int ldA, int ldB, int nt, int kSlice, int ldC,
    unsigned short* __restrict__ outKbf, float* __restrict__ outC,
    float* __restrict__ rsum) {
  __shared__ alignas(16) char smem[32768];
  const int t = threadIdx.x;
  const int l = t & 63;
  const int w = t >> 6;  // 0..3

  // bijective XCD swizzle over the (x,y) plane (nwg % 8 == 0 here)
  const int nwg = gridDim.x * gridDim.y;
  const int lin = blockIdx.y * gridDim.x + blockIdx.x;
  const int lin2 = (lin & 7) * (nwg >> 3) + (lin >> 3);
  const int bx = lin2 % gridDim.x;
  const int by = lin2 / gridDim.x;
  const int bM = by * 128;
  const int bN = bx * 128;
  const int wm = (w >> 1) * 64;  // M-side wave offset
  const int wn = (w & 1) * 64;   // N-side wave offset
  const int kOff = blockIdx.z * kSlice;

  const unsigned short* Ag = Amat + (size_t)bM * ldA + kOff;
  const unsigned short* Bg = Bmat + (size_t)bN * ldB + kOff;

  // staging: wave w covers rows [w*32, w*32+32) via 2 instr x 16 rows.
  // lane: tile row = w*32 + i*16 + (l>>2); physical chunk l&3; source logical
  // chunk = (l&3) ^ ((row>>1)&3)  (pre-swizzle).
  const int st_r0 = w * 32 + (l >> 2);        // i=0 row
  const int st_c0 = (((l & 3) ^ ((st_r0 >> 1) & 3)) * 8);
  const int st_r1 = st_r0 + 16;               // i=1 row
  const int st_c1 = (((l & 3) ^ ((st_r1 >> 1) & 3)) * 8);
  const int st_lds = w * 2048;                // wave-uniform, linear

  // ds_read: row = frag_base + (l&15); swizzled chunk = (l>>4) ^ ((row>>1)&3)
  const int rsw = ((l >> 4) ^ (((l & 15) >> 1) & 3)) * 16;
  const int arow = l & 15;

  auto stageA = [&](int k, char* buf) {
    const unsigned short* g = Ag + (size_t)st_r0 * ldA + k * 32;
    gload16(g + st_c0, buf + st_lds);
    gload16(g + (size_t)16 * ldA + st_c1, buf + st_lds + 1024);
  };
  auto stageB = [&](int k, char* buf) {
    const unsigned short* g = Bg + (size_t)st_r0 * ldB + k * 32;
    gload16(g + st_c0, buf + 8192 + st_lds);
    gload16(g + (size_t)16 * ldB + st_c1, buf + 8192 + st_lds + 1024);
  };

  f32x4 acc[4][4] = {};

  stageA(0, smem); stageB(0, smem);
  asm volatile("s_waitcnt vmcnt(0)" ::: "memory");
  bar_raw();
  sb0();

  for (int k = 0; k < nt; ++k) {
    char* cur = smem + (k & 1) * 16384;
    char* nxt = smem + ((k & 1) ^ 1) * 16384;
    if (k + 1 < nt) { stageA(k + 1, nxt); stageB(k + 1, nxt); }

    bf16x8 af[4], bf[4];
#pragma unroll
    for (int m = 0; m < 4; ++m)
      af[m] = ds_read16((lds_cp)(cur + (wm + m * 16 + arow) * 64 + rsw));
#pragma unroll
    for (int n = 0; n < 4; ++n)
      bf[n] = ds_read16((lds_cp)(cur + 8192 + (wn + n * 16 + arow) * 64 + rsw));
    lgkm_wait0();
    sb0();
    __builtin_amdgcn_s_setprio(1);
#pragma unroll
    for (int m = 0; m < 4; ++m)
#pragma unroll
      for (int n = 0; n < 4; ++n)
        acc[m][n] = __builtin_amdgcn_mfma_f32_16x16x32_bf16(af[m], bf[n], acc[m][n], 0, 0, 0);
    __builtin_amdgcn_s_setprio(0);
    sb0();
    if (k + 1 < nt) asm volatile("s_waitcnt vmcnt(0)" ::: "memory");
    bar_raw();
    sb0();
  }

  // epilogue: D row = (lane>>4)*4 + r, col = lane&15
  if (EPI == 0) {
#pragma unroll
    for (int m = 0; m < 4; ++m) {
#pragma unroll
      for (int r = 0; r < 4; ++r) {
        const int i = bM + wm + m * 16 + (l >> 4) * 4 + r;
        float rs = 0.0f;
#pragma unroll
        for (int n = 0; n < 4; ++n) {
          const int j = bN + wn + n * 16 + (l & 15);
          const float kvf = __expf(10.0f * acc[m][n][r]);
          outKbf[(size_t)i * ldC + j] = f2bf(kvf);
          rs += kvf;
        }
        rs += __shfl_xor(rs, 1); rs += __shfl_xor(rs, 2);
        rs += __shfl_xor(rs, 4); rs += __shfl_xor(rs, 8);
        if ((l & 15) == 0) unsafeAtomicAdd(&rsum[i], rs);
      }
    }
  } else {
#pragma unroll
    for (int m = 0; m < 4; ++m)
#pragma unroll
      for (int n = 0; n < 4; ++n)
#pragma unroll
        for (int r = 0; r < 4; ++r) {
          const int i = bM + wm + m * 16 + (l >> 4) * 4 + r;
          const int j = bN + wn + n * 16 + (l & 15);
          unsafeAtomicAdd(&outC[(size_t)i * ldC + j], acc[m][n][r]);
        }
  }
}

// --------------------------- sinkhorn pieces -------------------------------
__global__ __launch_bounds__(256) void zero_small(float* p) {
  p[blockIdx.x * 256 + threadIdx.x] = 0.0f;
}

__global__ __launch_bounds__(256) void zero_f32(float4* p) {
  p[(size_t)blockIdx.x * 256 + threadIdx.x] = float4{0.f, 0.f, 0.f, 0.f};
}

// s2[j] += sum_i u(rsum[i]) * K[i][j]; coalesced row-major reads.
__global__ __launch_bounds__(256) void colsum_u(
    const unsigned short* __restrict__ K, const float* __restrict__ rsum,
    float* __restrict__ s2) {
  __shared__ float part[8][256];
  const int j0 = blockIdx.x * 256;
  const int i0 = blockIdx.y * 128;
  const int c = (threadIdx.x & 31) * 8;
  const int rg = threadIdx.x >> 5;
  float acc[8] = {};
  for (int i = rg; i < 128; i += 8) {
    const float ui = pow_fi_of(rsum[i0 + i]);
    ushort8 kv = *(const ushort8*)(K + (size_t)(i0 + i) * N_TOK + j0 + c);
#pragma unroll
    for (int e = 0; e < 8; ++e) acc[e] += ui * bf2f(kv[e]);
  }
#pragma unroll
  for (int e = 0; e < 8; ++e) part[rg][c + e] = acc[e];
  __syncthreads();
  float s = 0.0f;
#pragma unroll
  for (int g = 0; g < 8; ++g) s += part[g][threadIdx.x];
  unsafeAtomicAdd(&s2[j0 + threadIdx.x], s);
}

// ------ T = (logK)/10 * (u K v) + delta -> bf16 (u,v inline from sums) -----
__global__ __launch_bounds__(256) void build_T(
    const unsigned short* __restrict__ Kbf,
    const float* __restrict__ delta, const float* __restrict__ rsum,
    const float* __restrict__ s2, unsigned short* __restrict__ Tbf) {
  const size_t e = ((size_t)blockIdx.x * 256 + threadIdx.x) * 8;
  const int i = (int)(e >> 12);
  const int j = (int)(e & 4095);
  const float ui = pow_fi_of(rsum[i]);
  ushort8 kv = *(const ushort8*)(Kbf + e);
  float4 d0 = *(const float4*)(delta + e);
  float4 d1 = *(const float4*)(delta + e + 4);
  float4 t0 = *(const float4*)(s2 + j);
  float4 t1 = *(const float4*)(s2 + j + 4);
  float v0x = pow_fi_of(t0.x), v0y = pow_fi_of(t0.y), v0z = pow_fi_of(t0.z), v0w = pow_fi_of(t0.w);
  float v1x = pow_fi_of(t1.x), v1y = pow_fi_of(t1.y), v1z = pow_fi_of(t1.z), v1w = pow_fi_of(t1.w);
  ushort8 o;
  float k0 = bf2f(kv[0]), k1 = bf2f(kv[1]), k2 = bf2f(kv[2]), k3 = bf2f(kv[3]);
  float k4 = bf2f(kv[4]), k5 = bf2f(kv[5]), k6 = bf2f(kv[6]), k7 = bf2f(kv[7]);
  o[0] = f2bf(0.1f * __logf(k0) * (ui * k0 * v0x) + d0.x);
  o[1] = f2bf(0.1f * __logf(k1) * (ui * k1 * v0y) + d0.y);
  o[2] = f2bf(0.1f * __logf(k2) * (ui * k2 * v0z) + d0.z);
  o[3] = f2bf(0.1f * __logf(k3) * (ui * k3 * v0w) + d0.w);
  o[4] = f2bf(0.1f * __logf(k4) * (ui * k4 * v1x) + d1.x);
  o[5] = f2bf(0.1f * __logf(k5) * (ui * k5 * v1y) + d1.y);
  o[6] = f2bf(0.1f * __logf(k6) * (ui * k6 * v1z) + d1.z);
  o[7] = f2bf(0.1f * __logf(k7) * (ui * k7 * v1w) + d1.w);
  *(ushort8*)(Tbf + e) = o;
}

// ---------------------------------------------------------------------------
extern "C" void kernel_launch(void* const* d_in, const int* in_sizes, int n_in,
                              void* d_out, int out_size, void* d_ws, size_t ws_size,
                              hipStream_t stream) {
  const float* X = (const float*)d_in[0];
  const float* Y = (const float*)d_in[1];
  const float* delta = (const float*)d_in[2];
  float* out = (float*)d_out;
  uint8_t* ws = (uint8_t*)d_ws;

  const size_t SZ_NN_BF = (size_t)N_TOK * N_TOK * 2;  // 32 MiB
  const size_t SZ_ND_BF = (size_t)N_TOK * D_EMB * 2;  // 16 MiB

  unsigned short* K_bf = (unsigned short*)(ws);                  // [0,32M)
  unsigned short* T_bf = (unsigned short*)(ws + SZ_NN_BF);       // [32M,64M)
  unsigned short* Xn = (unsigned short*)(ws + 2 * SZ_NN_BF);     // [64M,80M)
  unsigned short* XT = Xn;                                       // Xn dead after GEMM1
  float* rsum = (float*)(ws + 2 * SZ_NN_BF + SZ_ND_BF);          // [80M, +16K)
  float* s2 = rsum + N_TOK;
  unsigned short* Yn = (unsigned short*)d_out;  // scratch in out buf; dead before zero

  // 0) zero rsum+s2 (contiguous 8192 floats)
  zero_small<<<32, 256, 0, stream>>>(rsum);
  // 1) normalize rows -> bf16
  rownorm_bf16<<<N_TOK, 256, 0, stream>>>(X, Xn);
  rownorm_bf16<<<N_TOK, 256, 0, stream>>>(Y, Yn);
  // 2) K = exp(10 * Xn @ Yn^T), fused rowsum atomics  [grid 1024 = 4/CU]
  gemm128<0><<<dim3(32, 32, 1), 256, 0, stream>>>(
      Xn, Yn, D_EMB, D_EMB, D_EMB / 32, 0, N_TOK, K_bf, nullptr, rsum);
  // 3) out := 0 (split-K atomics; frees Yn), XT = bf16(X^T)
  zero_f32<<<(N_TOK * D_EMB / 4) / 256, 256, 0, stream>>>((float4*)out);
  transpose_f32_to_bf16<<<dim3(D_EMB / 32, N_TOK / 32), dim3(32, 8), 0, stream>>>(
      X, XT, N_TOK, D_EMB);
  // 4) s2 = colsum(u * K)  (u inline from rsum)
  colsum_u<<<dim3(16, 32), 256, 0, stream>>>(K_bf, rsum, s2);
  // 5) T = (logK)/10 * (u K v) + delta  (u,v inline from rsum,s2)
  build_T<<<(N_TOK / 8) * (N_TOK / 256), 256, 0, stream>>>(K_bf, delta, rsum, s2, T_bf);
  // 6) out += T @ X == NT(T, X^T), split-K=2  [grid 1024 = 4/CU]
  gemm128<1><<<dim3(D_EMB / 128, N_TOK / 128, 2), 256, 0, stream>>>(
      T_bf, XT, N_TOK, N_TOK, D_EMB / 32, D_EMB, D_EMB, nullptr, out, nullptr);
}

// Round 12
// 208.325 us; speedup vs baseline: 1.3267x; 1.3267x over previous
//
#include <hip/hip_runtime.h>
#include <stdint.h>

// ---------------------------------------------------------------------------
// TokenAlignerOT: A = cos(X,Y); K = exp(10A); ONE unbalanced-Sinkhorn
// iteration; T = (log K)/10 * (u K v^T) + delta; out = T @ X.
// Round 12 = round 11 with the GEMM2 K-depth bug fixed: out = T @ X reduces
// over N_TOK=4096 -> nt = 64 (r11 passed 32 = half the sum, absmax 6.4).
// GEMM1 = gemm256w4 (4 waves, 128x128/wave, ~102 us). GEMM2 = gemm_t2
// (256Mx128N, 4 waves, direct f32 stores, grid 256 = 1/CU, no split-K).
// Workspace: 80 MiB + 16 KiB of d_ws.
// ---------------------------------------------------------------------------

typedef __attribute__((ext_vector_type(8))) __bf16 bf16x8;
typedef __attribute__((ext_vector_type(4))) float f32x4;
typedef __attribute__((ext_vector_type(8))) unsigned short ushort8;

#define N_TOK 4096
#define D_EMB 2048
#define FI 0.009900990099009901f   /* reg_m/(reg_m+reg) = 0.001/0.101 */
#define LOG2A (-12.0f)             /* log2(1/4096) */

__device__ __forceinline__ unsigned short f2bf(float f) {
  union { float f; uint32_t u; } c; c.f = f;
  uint32_t r = (c.u + 0x7FFFu + ((c.u >> 16) & 1u)) >> 16;
  return (unsigned short)r;
}
__device__ __forceinline__ float bf2f(unsigned short h) {
  union { uint32_t u; float f; } c; c.u = ((uint32_t)h) << 16;
  return c.f;
}
__device__ __forceinline__ float pow_fi_of(float s) {
  return exp2f(FI * (LOG2A - log2f(s)));
}

// async global->LDS, 16 B per lane; LDS dest is wave-uniform base (+lane*16 HW)
typedef const __attribute__((address_space(1))) unsigned int* as1_u32p;
typedef __attribute__((address_space(3))) unsigned int* as3_u32p;
__device__ __forceinline__ void gload16(const void* g, void* l) {
  __builtin_amdgcn_global_load_lds((as1_u32p)g, (as3_u32p)l, 16, 0, 0);
}

// inline-asm LDS read: invisible to SIInsertWaitcnts' LDS-DMA aliasing.
typedef __attribute__((address_space(3))) const char* lds_cp;
__device__ __forceinline__ bf16x8 ds_read16(lds_cp p) {
  bf16x8 r;
  asm volatile("ds_read_b128 %0, %1" : "=v"(r) : "v"(p));
  return r;
}

__device__ __forceinline__ void bar_raw() {
  asm volatile("s_barrier" ::: "memory");
}
__device__ __forceinline__ void sb0() { __builtin_amdgcn_sched_barrier(0); }
__device__ __forceinline__ void lgkm_wait0() {
  asm volatile("s_waitcnt lgkmcnt(0)" ::: "memory");
}

// --------------------------- row L2-normalize -> bf16 ----------------------
__global__ __launch_bounds__(256) void rownorm_bf16(const float* __restrict__ in,
                                                    unsigned short* __restrict__ out) {
  const int row = blockIdx.x;
  const int t = threadIdx.x;
  const float* r = in + (size_t)row * D_EMB;
  float4 a = *(const float4*)(r + t * 8);
  float4 b = *(const float4*)(r + t * 8 + 4);
  float s = a.x * a.x + a.y * a.y + a.z * a.z + a.w * a.w
          + b.x * b.x + b.y * b.y + b.z * b.z + b.w * b.w;
#pragma unroll
  for (int off = 32; off; off >>= 1) s += __shfl_xor(s, off);
  __shared__ float wsum[4];
  if ((t & 63) == 0) wsum[t >> 6] = s;
  __syncthreads();
  float tot = wsum[0] + wsum[1] + wsum[2] + wsum[3];
  float scale = 1.0f / fmaxf(sqrtf(tot), 1e-8f);
  ushort8 o;
  o[0] = f2bf(a.x * scale); o[1] = f2bf(a.y * scale);
  o[2] = f2bf(a.z * scale); o[3] = f2bf(a.w * scale);
  o[4] = f2bf(b.x * scale); o[5] = f2bf(b.y * scale);
  o[6] = f2bf(b.z * scale); o[7] = f2bf(b.w * scale);
  *(ushort8*)(out + (size_t)row * D_EMB + t * 8) = o;
}

// --------------------------- transpose X -> bf16 X^T ------------------------
__global__ __launch_bounds__(256) void transpose_f32_to_bf16(
    const float* __restrict__ in, unsigned short* __restrict__ out, int R, int C) {
  __shared__ float tile[32][33];
  const int bi = blockIdx.y * 32, bj = blockIdx.x * 32;
  const int tx = threadIdx.x, ty = threadIdx.y;
#pragma unroll
  for (int dy = 0; dy < 32; dy += 8)
    tile[ty + dy][tx] = in[(size_t)(bi + ty + dy) * C + bj + tx];
  __syncthreads();
#pragma unroll
  for (int dy = 0; dy < 32; dy += 8)
    out[(size_t)(bj + ty + dy) * R + bi + tx] = f2bf(tile[tx][ty + dy]);
}

// ============ GEMM1: 256x256 NT, 4 waves, 128x128/wave (r9-best) ===========
__global__ __launch_bounds__(256, 1) void gemm256w4(
    const unsigned short* __restrict__ Amat, const unsigned short* __restrict__ Bmat,
    int ldA, int ldB, int nt, int ldC,
    unsigned short* __restrict__ outKbf, float* __restrict__ rsum) {
  __shared__ alignas(16) char smem[131072];
  const int t = threadIdx.x;
  const int l = t & 63;
  const int w = t >> 6;  // 0..3

  const int nwg = gridDim.x * gridDim.y;
  const int lin = blockIdx.y * gridDim.x + blockIdx.x;
  const int lin2 = (lin & 7) * (nwg >> 3) + (lin >> 3);
  const int bx = lin2 % gridDim.x;
  const int by = lin2 / gridDim.x;
  const int bM = by * 256;
  const int bN = bx * 256;
  const int wrow = w >> 1;  // 0..1
  const int wcol = w & 1;   // 0..1

  const unsigned short* Ag = Amat + (size_t)bM * ldA;
  const unsigned short* Bg = Bmat + (size_t)bN * ldB;

  const int st_row = w * 64 + (l >> 3);
  const int st_col = ((l & 7) ^ (l >> 3)) * 8;
  const int st_lds = w * 8192;

  const int rsw0 = (((l >> 4) + 0) ^ (l & 7)) * 16;
  const int rsw1 = (((l >> 4) + 4) ^ (l & 7)) * 16;
  const int arow = l & 15;

  auto stageA = [&](int k) {
    char* base = smem + (k & 1) * 32768 + st_lds;
    const unsigned short* g = Ag + (size_t)st_row * ldA + k * 64 + st_col;
#pragma unroll
    for (int i = 0; i < 8; ++i)
      gload16(g + (size_t)(i * 8) * ldA, base + i * 1024);
  };
  auto stageB = [&](int k) {
    char* base = smem + 65536 + (k & 1) * 32768 + st_lds;
    const unsigned short* g = Bg + (size_t)st_row * ldB + k * 64 + st_col;
#pragma unroll
    for (int i = 0; i < 8; ++i)
      gload16(g + (size_t)(i * 8) * ldB, base + i * 1024);
  };

  f32x4 acc[8][8] = {};

  stageA(0); stageB(0);
  asm volatile("s_waitcnt vmcnt(0)" ::: "memory");
  bar_raw();
  sb0();

  for (int k = 0; k < nt; ++k) {
    char* Abase = smem + (k & 1) * 32768;
    char* Bbase = smem + 65536 + (k & 1) * 32768;
    if (k + 1 < nt) { stageA(k + 1); stageB(k + 1); }

#pragma unroll
    for (int kk = 0; kk < 2; ++kk) {
      const int rsw = kk ? rsw1 : rsw0;
      bf16x8 af[8], bf[8];
#pragma unroll
      for (int m = 0; m < 8; ++m)
        af[m] = ds_read16((lds_cp)(Abase + (wrow * 128 + m * 16 + arow) * 128 + rsw));
#pragma unroll
      for (int n = 0; n < 8; ++n)
        bf[n] = ds_read16((lds_cp)(Bbase + (wcol * 128 + n * 16 + arow) * 128 + rsw));
      lgkm_wait0();
      sb0();
      __builtin_amdgcn_s_setprio(1);
#pragma unroll
      for (int m = 0; m < 8; ++m)
#pragma unroll
        for (int n = 0; n < 8; ++n)
          acc[m][n] = __builtin_amdgcn_mfma_f32_16x16x32_bf16(af[m], bf[n], acc[m][n], 0, 0, 0);
      __builtin_amdgcn_s_setprio(0);
      sb0();
    }

    asm volatile("s_waitcnt vmcnt(0)" ::: "memory");
    bar_raw();
    sb0();
  }

  // epilogue: D row = (lane>>4)*4 + r, col = lane&15; fused rowsum(exp)
#pragma unroll
  for (int m = 0; m < 8; ++m) {
#pragma unroll
    for (int r = 0; r < 4; ++r) {
      const int i = bM + wrow * 128 + m * 16 + (l >> 4) * 4 + r;
      float rs = 0.0f;
#pragma unroll
      for (int n = 0; n < 8; ++n) {
        const int j = bN + wcol * 128 + n * 16 + (l & 15);
        const float kvf = __expf(10.0f * acc[m][n][r]);
        outKbf[(size_t)i * ldC + j] = f2bf(kvf);
        rs += kvf;
      }
      rs += __shfl_xor(rs, 1); rs += __shfl_xor(rs, 2);
      rs += __shfl_xor(rs, 4); rs += __shfl_xor(rs, 8);
      if ((l & 15) == 0) unsafeAtomicAdd(&rsum[i], rs);
    }
  }
}

// ============ GEMM2: 256Mx128N NT, 4 waves, direct f32 stores ==============
// out[i][j] = sum_{k<N_TOK} T[i][k] * XT[j][k]; nt = N_TOK/64 = 64.
// grid (16,16)=256 blocks, wave = 128x64 (2Mx2N). LDS 96 KiB.
__global__ __launch_bounds__(256, 1) void gemm_t2(
    const unsigned short* __restrict__ Amat, const unsigned short* __restrict__ Bmat,
    int ldA, int ldB, int nt, int ldC, float* __restrict__ outC) {
  __shared__ alignas(16) char smem[98304];
  const int t = threadIdx.x;
  const int l = t & 63;
  const int w = t >> 6;  // 0..3

  const int nwg = gridDim.x * gridDim.y;
  const int lin = blockIdx.y * gridDim.x + blockIdx.x;
  const int lin2 = (lin & 7) * (nwg >> 3) + (lin >> 3);
  const int bx = lin2 % gridDim.x;   // N dir (16): bN = bx*128
  const int by = lin2 / gridDim.x;   // M dir (16): bM = by*256
  const int bM = by * 256;
  const int bN = bx * 128;
  const int wrow = w >> 1;  // 0..1 -> M offset wrow*128
  const int wcol = w & 1;   // 0..1 -> N offset wcol*64

  const unsigned short* Ag = Amat + (size_t)bM * ldA;
  const unsigned short* Bg = Bmat + (size_t)bN * ldB;

  const int stA_row = w * 64 + (l >> 3);
  const int st_col = ((l & 7) ^ (l >> 3)) * 8;
  const int stA_lds = w * 8192;
  const int stB_row = w * 32 + (l >> 3);
  const int stB_lds = w * 4096;

  const int rsw0 = (((l >> 4) + 0) ^ (l & 7)) * 16;
  const int rsw1 = (((l >> 4) + 4) ^ (l & 7)) * 16;
  const int arow = l & 15;

  auto stageA = [&](int k) {
    char* base = smem + (k & 1) * 32768 + stA_lds;
    const unsigned short* g = Ag + (size_t)stA_row * ldA + k * 64 + st_col;
#pragma unroll
    for (int i = 0; i < 8; ++i)
      gload16(g + (size_t)(i * 8) * ldA, base + i * 1024);
  };
  auto stageB = [&](int k) {
    char* base = smem + 65536 + (k & 1) * 16384 + stB_lds;
    const unsigned short* g = Bg + (size_t)stB_row * ldB + k * 64 + st_col;
#pragma unroll
    for (int i = 0; i < 4; ++i)
      gload16(g + (size_t)(i * 8) * ldB, base + i * 1024);
  };

  f32x4 acc[8][4] = {};

  stageA(0); stageB(0);
  asm volatile("s_waitcnt vmcnt(0)" ::: "memory");
  bar_raw();
  sb0();

  for (int k = 0; k < nt; ++k) {
    char* Abase = smem + (k & 1) * 32768;
    char* Bbase = smem + 65536 + (k & 1) * 16384;
    if (k + 1 < nt) { stageA(k + 1); stageB(k + 1); }

#pragma unroll
    for (int kk = 0; kk < 2; ++kk) {
      const int rsw = kk ? rsw1 : rsw0;
      bf16x8 af[8], bf[4];
#pragma unroll
      for (int m = 0; m < 8; ++m)
        af[m] = ds_read16((lds_cp)(Abase + (wrow * 128 + m * 16 + arow) * 128 + rsw));
#pragma unroll
      for (int n = 0; n < 4; ++n)
        bf[n] = ds_read16((lds_cp)(Bbase + (wcol * 64 + n * 16 + arow) * 128 + rsw));
      lgkm_wait0();
      sb0();
      __builtin_amdgcn_s_setprio(1);
#pragma unroll
      for (int m = 0; m < 8; ++m)
#pragma unroll
        for (int n = 0; n < 4; ++n)
          acc[m][n] = __builtin_amdgcn_mfma_f32_16x16x32_bf16(af[m], bf[n], acc[m][n], 0, 0, 0);
      __builtin_amdgcn_s_setprio(0);
      sb0();
    }

    asm volatile("s_waitcnt vmcnt(0)" ::: "memory");
    bar_raw();
    sb0();
  }

  // epilogue: direct f32 stores (no atomics)
#pragma unroll
  for (int m = 0; m < 8; ++m)
#pragma unroll
    for (int n = 0; n < 4; ++n)
#pragma unroll
      for (int r = 0; r < 4; ++r) {
        const int i = bM + wrow * 128 + m * 16 + (l >> 4) * 4 + r;
        const int j = bN + wcol * 64 + n * 16 + (l & 15);
        outC[(size_t)i * ldC + j] = acc[m][n][r];
      }
}

// --------------------------- sinkhorn pieces -------------------------------
__global__ __launch_bounds__(256) void zero_small(float* p) {
  p[blockIdx.x * 256 + threadIdx.x] = 0.0f;
}

// s2[j] += sum_i u(rsum[i]) * K[i][j]; coalesced row-major reads.
__global__ __launch_bounds__(256) void colsum_u(
    const unsigned short* __restrict__ K, const float* __restrict__ rsum,
    float* __restrict__ s2) {
  __shared__ float part[8][256];
  const int j0 = blockIdx.x * 256;
  const int i0 = blockIdx.y * 128;
  const int c = (threadIdx.x & 31) * 8;
  const int rg = threadIdx.x >> 5;
  float acc[8] = {};
  for (int i = rg; i < 128; i += 8) {
    const float ui = pow_fi_of(rsum[i0 + i]);
    ushort8 kv = *(const ushort8*)(K + (size_t)(i0 + i) * N_TOK + j0 + c);
#pragma unroll
    for (int e = 0; e < 8; ++e) acc[e] += ui * bf2f(kv[e]);
  }
#pragma unroll
  for (int e = 0; e < 8; ++e) part[rg][c + e] = acc[e];
  __syncthreads();
  float s = 0.0f;
#pragma unroll
  for (int g = 0; g < 8; ++g) s += part[g][threadIdx.x];
  unsafeAtomicAdd(&s2[j0 + threadIdx.x], s);
}

// ------ T = (logK)/10 * (u K v) + delta -> bf16 (u,v inline from sums) -----
__global__ __launch_bounds__(256) void build_T(
    const unsigned short* __restrict__ Kbf,
    const float* __restrict__ delta, const float* __restrict__ rsum,
    const float* __restrict__ s2, unsigned short* __restrict__ Tbf) {
  const size_t e = ((size_t)blockIdx.x * 256 + threadIdx.x) * 8;
  const int i = (int)(e >> 12);
  const int j = (int)(e & 4095);
  const float ui = pow_fi_of(rsum[i]);
  ushort8 kv = *(const ushort8*)(Kbf + e);
  float4 d0 = *(const float4*)(delta + e);
  float4 d1 = *(const float4*)(delta + e + 4);
  float4 t0 = *(const float4*)(s2 + j);
  float4 t1 = *(const float4*)(s2 + j + 4);
  float v0x = pow_fi_of(t0.x), v0y = pow_fi_of(t0.y), v0z = pow_fi_of(t0.z), v0w = pow_fi_of(t0.w);
  float v1x = pow_fi_of(t1.x), v1y = pow_fi_of(t1.y), v1z = pow_fi_of(t1.z), v1w = pow_fi_of(t1.w);
  ushort8 o;
  float k0 = bf2f(kv[0]), k1 = bf2f(kv[1]), k2 = bf2f(kv[2]), k3 = bf2f(kv[3]);
  float k4 = bf2f(kv[4]), k5 = bf2f(kv[5]), k6 = bf2f(kv[6]), k7 = bf2f(kv[7]);
  o[0] = f2bf(0.1f * __logf(k0) * (ui * k0 * v0x) + d0.x);
  o[1] = f2bf(0.1f * __logf(k1) * (ui * k1 * v0y) + d0.y);
  o[2] = f2bf(0.1f * __logf(k2) * (ui * k2 * v0z) + d0.z);
  o[3] = f2bf(0.1f * __logf(k3) * (ui * k3 * v0w) + d0.w);
  o[4] = f2bf(0.1f * __logf(k4) * (ui * k4 * v1x) + d1.x);
  o[5] = f2bf(0.1f * __logf(k5) * (ui * k5 * v1y) + d1.y);
  o[6] = f2bf(0.1f * __logf(k6) * (ui * k6 * v1z) + d1.z);
  o[7] = f2bf(0.1f * __logf(k7) * (ui * k7 * v1w) + d1.w);
  *(ushort8*)(Tbf + e) = o;
}

// ---------------------------------------------------------------------------
extern "C" void kernel_launch(void* const* d_in, const int* in_sizes, int n_in,
                              void* d_out, int out_size, void* d_ws, size_t ws_size,
                              hipStream_t stream) {
  const float* X = (const float*)d_in[0];
  const float* Y = (const float*)d_in[1];
  const float* delta = (const float*)d_in[2];
  float* out = (float*)d_out;
  uint8_t* ws = (uint8_t*)d_ws;

  const size_t SZ_NN_BF = (size_t)N_TOK * N_TOK * 2;  // 32 MiB
  const size_t SZ_ND_BF = (size_t)N_TOK * D_EMB * 2;  // 16 MiB

  unsigned short* K_bf = (unsigned short*)(ws);                  // [0,32M)
  unsigned short* T_bf = (unsigned short*)(ws + SZ_NN_BF);       // [32M,64M)
  unsigned short* Xn = (unsigned short*)(ws + 2 * SZ_NN_BF);     // [64M,80M)
  unsigned short* XT = Xn;                                       // Xn dead after GEMM1
  float* rsum = (float*)(ws + 2 * SZ_NN_BF + SZ_ND_BF);          // [80M, +16K)
  float* s2 = rsum + N_TOK;
  unsigned short* Yn = (unsigned short*)d_out;  // parked; overwritten by gemm_t2

  // 0) zero rsum+s2 (contiguous 8192 floats)
  zero_small<<<32, 256, 0, stream>>>(rsum);
  // 1) normalize rows -> bf16
  rownorm_bf16<<<N_TOK, 256, 0, stream>>>(X, Xn);
  rownorm_bf16<<<N_TOK, 256, 0, stream>>>(Y, Yn);
  // 2) K = exp(10 * Xn @ Yn^T), fused rowsum atomics
  gemm256w4<<<dim3(16, 16, 1), 256, 0, stream>>>(
      Xn, Yn, D_EMB, D_EMB, D_EMB / 64, N_TOK, K_bf, rsum);
  // 3) XT = bf16(X^T)  (overwrites Xn slot)
  transpose_f32_to_bf16<<<dim3(D_EMB / 32, N_TOK / 32), dim3(32, 8), 0, stream>>>(
      X, XT, N_TOK, D_EMB);
  // 4) s2 = colsum(u * K)  (u inline from rsum)
  colsum_u<<<dim3(16, 32), 256, 0, stream>>>(K_bf, rsum, s2);
  // 5) T = (logK)/10 * (u K v) + delta  (u,v inline from rsum,s2)
  build_T<<<(N_TOK / 8) * (N_TOK / 256), 256, 0, stream>>>(K_bf, delta, rsum, s2, T_bf);
  // 6) out = T @ X == NT(T, X^T), nt = N_TOK/64 = 64, direct stores
  gemm_t2<<<dim3(16, 16, 1), 256, 0, stream>>>(
      T_bf, XT, N_TOK, N_TOK, N_TOK / 64, D_EMB, out);
}